// Round 9
// baseline (270.566 us; speedup 1.0000x reference)
//
#include <hip/hip_runtime.h>
#include <hip/hip_bf16.h>
#include <stdint.h>

// Problem: 3x Bahdanau attention (p/c/h heads) -> averaged softmax weights -> weighted sum of sentence.
// S=8192, H2=1024, A=2048, E=768. All inputs fp32; output fp32 [1024].
// R8: 213.5us, gemm 54.6 (64x128, gl_lds, depth-2 vmcnt(3), XCD map). FETCH 53->22MB with zero
//     time delta => not memory-bound.
// R9: pitch-40 reg-staged LDS: conflicts DOUBLED (8.55M), gemm 60.1. Bank model not predictive;
//     conflicts are a ~7us secondary term. Real bound: LDS instruction pipe (~24 b128 reads +
//     stage writes ~330cyc/block-iter vs 128cyc MFMA). We're at 435TF, above m97-structure's
//     ~320TF reference for this N~2048 shape.
// R10: remove A from LDS entirely: per-lane direct global loads of the 32B A fragment
//     (L2-hot via XCD map), fp32->bf16 cvt in-register. LDS ops/iter 27->18; LDS 37->24.8KB;
//     prep phase 1 (sentence cvt, 4096 blocks, 12MB) DELETED -- gemm reads fp32 sentence.
//     Depth-2 counted pipeline: S(t)={4 A-loads + 2 B-gl_lds}; in-loop wait vmcnt(6) = tile
//     t+1 landed while t+2 stays in flight. Static slots/bufs via 6-unroll (rule #20).

namespace {

constexpr int S = 8192;
constexpr int H = 1024;   // H2
constexpr int A = 2048;
constexpr int E = 768;

typedef __bf16 bf16x8 __attribute__((ext_vector_type(8)));
typedef float f32x4 __attribute__((ext_vector_type(4)));

__device__ __forceinline__ void gl_lds16(const void* g, void* l) {
  __builtin_amdgcn_global_load_lds(
      (const __attribute__((address_space(1))) void*)g,
      (__attribute__((address_space(3))) void*)l, 16, 0, 0);
}

__device__ __forceinline__ bf16x8 cvt8(float4 lo, float4 hi) {
  bf16x8 r;
  r[0] = (__bf16)lo.x; r[1] = (__bf16)lo.y; r[2] = (__bf16)lo.z; r[3] = (__bf16)lo.w;
  r[4] = (__bf16)hi.x; r[5] = (__bf16)hi.y; r[6] = (__bf16)hi.z; r[7] = (__bf16)hi.w;
  return r;
}

// ---------- merged prep (phase 1 deleted: gemm reads fp32 sentence directly) ----------
// [0,1536)      transpose W_sent fp32 [H][A] -> Wt [A][H] bf16  (float2 in / ushort2 out)
// [1536,1632)   ctxb_q[q][head][a] = partial ctx @ W_ctx over e-quarter q (+biases in q0)
// [1632,1640)   zero e_arr + out
__global__ __launch_bounds__(256)
void k_prep(const float* __restrict__ Wp, const float* __restrict__ Wc_s,
            const float* __restrict__ Wh, __bf16* __restrict__ WtB,
            const float* __restrict__ ctx_p, const float* __restrict__ ctx_c,
            const float* __restrict__ ctx_h,
            const float* __restrict__ Wcx_p, const float* __restrict__ Wcx_c,
            const float* __restrict__ Wcx_h,
            const float* __restrict__ bs_p, const float* __restrict__ bs_c,
            const float* __restrict__ bs_h,
            const float* __restrict__ bc_p, const float* __restrict__ bc_c,
            const float* __restrict__ bc_h,
            float* __restrict__ ctxb_q, float* __restrict__ e_arr,
            float* __restrict__ out, int n_out) {
  __shared__ float tile[64][65];
  int b = blockIdx.x;
  int t = threadIdx.x;

  if (b < 1536) {
    // ---- phase 1: W_sent [H][A] fp32 -> Wt [A][H] bf16, widened both sides ----
    int r = b;                        // 512 tiles per head
    int head = r >> 9; r &= 511;
    const float* W = head == 0 ? Wp : (head == 1 ? Wc_s : Wh);
    __bf16* dst = WtB + (size_t)head * A * H;
    int a0 = (r & 31) * 64;           // 32 a-tiles
    int k0 = (r >> 5) * 64;           // 16 k-tiles
#pragma unroll
    for (int i = 0; i < 8; ++i) {
      int idx = t + i * 256;
      int rr = idx >> 5;              // k-row 0..63
      int cc = (idx & 31) * 2;        // a-col pairs: float2 loads, 2-way LDS banks (free)
      float2 w2 = *(const float2*)&W[(size_t)(k0 + rr) * A + a0 + cc];
      tile[cc][rr] = w2.x;
      tile[cc + 1][rr] = w2.y;
    }
    __syncthreads();
#pragma unroll
    for (int i = 0; i < 8; ++i) {
      int idx = t + i * 256;
      int al = idx >> 5;              // a-row
      int kl = (idx & 31) * 2;        // k pair: ushort2 store, 256B/wave-segment
      union { ushort2 u; __bf16 h[2]; } o;
      o.h[0] = (__bf16)tile[al][kl];
      o.h[1] = (__bf16)tile[al][kl + 1];
      *(ushort2*)&dst[(size_t)(a0 + al) * H + k0 + kl] = o.u;
    }
  } else if (b < 1632) {
    // ---- phase 2: ctxb quarter-partials, direct store (no atomics -> no memset) ----
    int r = b - 1536;                 // 96 blocks: 3 heads x {8 a-blocks x 4 e-quarters}
    int head = r >> 5;
    int sub = r & 31;
    int ablk = sub & 7;
    int eq = sub >> 3;                // e-quarter: 192 elements
    const float* ctx = head == 0 ? ctx_p : (head == 1 ? ctx_c : ctx_h);
    const float* Wc  = head == 0 ? Wcx_p : (head == 1 ? Wcx_c : Wcx_h);
    int a = ablk * 256 + t;
    float s = 0.f;
    if (eq == 0) {
      const float* bs = head == 0 ? bs_p : (head == 1 ? bs_c : bs_h);
      const float* bc = head == 0 ? bc_p : (head == 1 ? bc_c : bc_h);
      s = bs[a] + bc[a];
    }
    int e0 = eq * 192;
#pragma unroll 8
    for (int e = e0; e < e0 + 192; ++e) s = fmaf(ctx[e], Wc[(size_t)e * A + a], s);
    ctxb_q[eq * 3 * A + head * A + a] = s;
  } else {
    // ---- phase 3: zero e_arr (6144 float4) + out ----
    int idx = (b - 1632) * 256 + t;   // 8 blocks x 256 threads = 2048 strides
    float4 z = {0.f, 0.f, 0.f, 0.f};
    int total = 6144 + (n_out >> 2);
    for (int i = idx; i < total; i += 2048) {
      if (i < 6144) ((float4*)e_arr)[i] = z;
      else ((float4*)out)[i - 6144] = z;
    }
  }
}

// ---------- GEMM + fused tanh*v epilogue -> e[head][s] ----------
// 64x128 tile, BK=32. A: per-lane direct global (fp32, 32B/lane contiguous, L2-hot via XCD
// map), cvt to bf16 in-register -- A never touches LDS. B: gl_lds into 3 bufs, 64B pitch.
// Depth-2: S(t) = 4 A-loads + 2 B-gl_lds; iter waits vmcnt(6) (= S(t+1) landed, S(t+2) in
// flight). Raw s_barrier + clobber-free waitcnt + sched_barrier(0) fences (R3 lesson).
// XCD panel-local mapping from R8: xcd=bid&7 owns 6 of 48 (n,head) panels, m outer.
__global__ __launch_bounds__(256)
void k_gemm_e(const float* __restrict__ sent, const __bf16* __restrict__ WtB,
              const float* __restrict__ ctxb_q,
              const float* __restrict__ v_p, const float* __restrict__ v_c,
              const float* __restrict__ v_h,
              const int* __restrict__ length, float* __restrict__ e_out) {
  int bid = blockIdx.x;
  int xcd = bid & 7;
  int j = bid >> 3;                  // [0, 768)
  int mt = j / 6;                    // m OUTER within XCD: 128 m-tiles
  int pl = j - mt * 6;               // 6 panels per XCD
  int panel = xcd * 6 + pl;          // [0, 48)
  int n0 = (panel & 15) * 128;
  int head = panel >> 4;

  int m0 = mt * 64;
  int len = min(max(length[0], 0), S);
  if (m0 >= len) return;          // masked rows can never influence the softmax
  const float* v  = head == 0 ? v_p : (head == 1 ? v_c : v_h);
  const __bf16* Wt = WtB + (size_t)head * A * H;
  float* e_h = e_out + head * S;

  __shared__ __align__(16) __bf16 lsB[3 * 4096];   // 3 bufs x [128 rows][32 k] = 24 KB
  __shared__ float e_part[64];

  int tid = threadIdx.x;
  if (tid < 64) e_part[tid] = 0.f;   // 33 barriers before the epilogue reads it

  int lane = tid & 63;
  int wave = tid >> 6;
  int wm = wave >> 1, wn = wave & 1;       // wave tile: 32 rows x 64 cols
  int quad = lane >> 4, l16 = lane & 15;

  f32x4 acc[2][4];
#pragma unroll
  for (int i = 0; i < 2; ++i)
#pragma unroll
    for (int j2 = 0; j2 < 4; ++j2) acc[i][j2] = (f32x4){0.f, 0.f, 0.f, 0.f};

  // B staging sources (coalesced 16B/thread)
  const __bf16* gB0 = Wt + (size_t)(n0 + (tid >> 2)) * H + ((tid & 3) * 8);
  const __bf16* gB1 = gB0 + (size_t)64 * H;
  // A fragment sources: lane (quad,l16) of wave (wm,*) owns rows m0+wm*32+{l16,16+l16},
  // k-slice quad*8..+8 (32B contiguous fp32). Identical data layout to the old LDS path.
  const float* gA0 = sent + (size_t)(m0 + wm * 32 + l16) * H + quad * 8;
  const float* gA1 = gA0 + (size_t)16 * H;

  float4 s0[4], s1[4];       // two A slots (fp32), static indices only
  bf16x8 ab0, ab1;           // current tile's A fragments (bf16)

#define AISSUE(sl, kk)                              \
  do {                                              \
    sl[0] = *(const float4*)(gA0 + (kk));           \
    sl[1] = *(const float4*)(gA0 + (kk) + 4);       \
    sl[2] = *(const float4*)(gA1 + (kk));           \
    sl[3] = *(const float4*)(gA1 + (kk) + 4);       \
  } while (0)

#define BISSUE(bufi, kk)                                          \
  do {                                                            \
    gl_lds16(gB0 + (kk), lsB + (bufi) * 4096 + tid * 8);          \
    gl_lds16(gB1 + (kk), lsB + (bufi) * 4096 + 2048 + tid * 8);   \
  } while (0)

#define ACVT(sl)                                    \
  do {                                              \
    ab0 = cvt8(sl[0], sl[1]);                       \
    ab1 = cvt8(sl[2], sl[3]);                       \
  } while (0)

#define COMPUTE(bufi)                                                                           \
  do {                                                                                          \
    bf16x8 bfv[4];                                                                              \
    _Pragma("unroll")                                                                           \
    for (int jj = 0; jj < 4; ++jj)                                                              \
      bfv[jj] = *(const bf16x8*)&lsB[(bufi) * 4096 + (wn * 64 + jj * 16 + l16) * 32 + quad * 8];\
    _Pragma("unroll")                                                                           \
    for (int jj = 0; jj < 4; ++jj) {                                                            \
      acc[0][jj] = __builtin_amdgcn_mfma_f32_16x16x32_bf16(ab0, bfv[jj], acc[0][jj], 0, 0, 0);  \
      acc[1][jj] = __builtin_amdgcn_mfma_f32_16x16x32_bf16(ab1, bfv[jj], acc[1][jj], 0, 0, 0);  \
    }                                                                                           \
  } while (0)

  // One iteration t: entry invariant = S(t+1)'s 6 vmem ops outstanding, buf t%3 ready, ab =
  // A(t). Issue S(t+2) (slot = t&1, freed when A(t) was cvt'd); COMPUTE(t); vmcnt(6) -> S(t+1)
  // landed; cvt A(t+1); barrier publishes B(t+1).
#define ITER(t, sIss, sCvt, bufC, bufN)             \
  do {                                              \
    AISSUE(sIss, ((t) + 2) * 32);                   \
    BISSUE(bufN, ((t) + 2) * 32);                   \
    COMPUTE(bufC);                                  \
    asm volatile("s_waitcnt vmcnt(6)");             \
    ACVT(sCvt);                                     \
    __builtin_amdgcn_sched_barrier(0);              \
    __builtin_amdgcn_s_barrier();                   \
    __builtin_amdgcn_sched_barrier(0);              \
  } while (0)

  // prologue: S(0), S(1) issued (12 ops); wait oldest 6 -> S(0) done; cvt A(0); barrier.
  AISSUE(s0, 0);
  BISSUE(0, 0);
  AISSUE(s1, 32);
  BISSUE(1, 32);
  asm volatile("s_waitcnt vmcnt(6)");
  ACVT(s0);
  __builtin_amdgcn_sched_barrier(0);
  __builtin_amdgcn_s_barrier();
  __builtin_amdgcn_sched_barrier(0);

#pragma unroll 1
  for (int r = 0; r < 5; ++r) {
    int tb = r * 6;
    ITER(tb + 0, s0, s1, 0, 2);
    ITER(tb + 1, s1, s0, 1, 0);
    ITER(tb + 2, s0, s1, 2, 1);
    ITER(tb + 3, s1, s0, 0, 2);
    ITER(tb + 4, s0, s1, 1, 0);
    ITER(tb + 5, s1, s0, 2, 1);
  }
  // tail: t=30 (buf 0; S(31) outstanding), t=31 (buf 1)
  COMPUTE(0);
  asm volatile("s_waitcnt vmcnt(0)");
  ACVT(s1);                      // A(31), issued at iter 29 into slot 1
  __builtin_amdgcn_sched_barrier(0);
  __builtin_amdgcn_s_barrier();
  __builtin_amdgcn_sched_barrier(0);
  COMPUTE(1);

#undef AISSUE
#undef BISSUE
#undef ACVT
#undef COMPUTE
#undef ITER

  float vj[4], cbj[4];
#pragma unroll
  for (int j2 = 0; j2 < 4; ++j2) {
    int col = n0 + wn * 64 + j2 * 16 + l16;
    vj[j2] = v[col];
    // sum the 4 e-quarter partials (L2-hot, 98KB table); biases folded into quarter 0
    cbj[j2] = ctxb_q[head * A + col] + ctxb_q[3 * A + head * A + col] +
              ctxb_q[6 * A + head * A + col] + ctxb_q[9 * A + head * A + col];
  }
#pragma unroll
  for (int i = 0; i < 2; ++i) {
#pragma unroll
    for (int r = 0; r < 4; ++r) {
      float p = 0.f;
#pragma unroll
      for (int j2 = 0; j2 < 4; ++j2) {
        float u = acc[i][j2][r] + cbj[j2];
        float ex = __expf(2.f * u);        // tanh = 1 - 2/(e^2x+1); inf-safe at both ends
        float th = 1.f - 2.f / (ex + 1.f);
        p = fmaf(th, vj[j2], p);
      }
      p += __shfl_xor(p, 1);
      p += __shfl_xor(p, 2);
      p += __shfl_xor(p, 4);
      p += __shfl_xor(p, 8);
      if (l16 == 0) atomicAdd(&e_part[wm * 32 + i * 16 + quad * 4 + r], p);
    }
  }
  __syncthreads();
  if (tid < 64) atomicAdd(&e_h[m0 + tid], e_part[tid]);
}

// ---------- softmax stats per head (max, sum) over s < len ----------
__global__ void k_stats(const float* __restrict__ e_arr, const int* __restrict__ length,
                        float* __restrict__ stats) {
  int head = blockIdx.x;
  const float* e_h = e_arr + head * S;
  int len = min(max(length[0], 0), S);
  int tid = threadIdx.x;
  __shared__ float red[4];
  __shared__ float bmax;

  float m = -3.4e38f;
  for (int s = tid; s < len; s += 256) m = fmaxf(m, e_h[s]);
#pragma unroll
  for (int o = 32; o >= 1; o >>= 1) m = fmaxf(m, __shfl_xor(m, o));
  if ((tid & 63) == 0) red[tid >> 6] = m;
  __syncthreads();
  if (tid == 0) bmax = fmaxf(fmaxf(red[0], red[1]), fmaxf(red[2], red[3]));
  __syncthreads();
  float mm = bmax;

  float ss = 0.f;
  for (int s = tid; s < len; s += 256) ss += __expf(e_h[s] - mm);
#pragma unroll
  for (int o = 32; o >= 1; o >>= 1) ss += __shfl_xor(ss, o);
  __syncthreads();
  if ((tid & 63) == 0) red[tid >> 6] = ss;
  __syncthreads();
  if (tid == 0) {
    stats[head * 2 + 0] = mm;
    stats[head * 2 + 1] = red[0] + red[1] + red[2] + red[3];
  }
}

// ---------- out[h] = sum_s w(s) * sentence[s][h], w from e+stats ----------
__global__ void k_out(const float* __restrict__ sent, const float* __restrict__ e_arr,
                      const float* __restrict__ stats, const int* __restrict__ length,
                      float* __restrict__ out) {
  int len = min(max(length[0], 0), S);
  int r0 = blockIdx.x * 16;
  if (r0 >= len) return;
  int tid = threadIdx.x;

  __shared__ float wrow[16];
  if (tid < 16 && r0 + tid < len) {
    int r = r0 + tid;
    wrow[tid] = (__expf(e_arr[r] - stats[0]) / stats[1] +
                 __expf(e_arr[S + r] - stats[2]) / stats[3] +
                 __expf(e_arr[2 * S + r] - stats[4]) / stats[5]) * (1.f / 3.f);
  }
  __syncthreads();

  int col = tid * 4;
  int rend = min(r0 + 16, len);
  float4 acc = {0.f, 0.f, 0.f, 0.f};
  for (int r = r0; r < rend; ++r) {
    float w = wrow[r - r0];
    float4 x = *(const float4*)(sent + (size_t)r * H + col);
    acc.x = fmaf(w, x.x, acc.x);
    acc.y = fmaf(w, x.y, acc.y);
    acc.z = fmaf(w, x.z, acc.z);
    acc.w = fmaf(w, x.w, acc.w);
  }
  atomicAdd(&out[col + 0], acc.x);
  atomicAdd(&out[col + 1], acc.y);
  atomicAdd(&out[col + 2], acc.z);
  atomicAdd(&out[col + 3], acc.w);
}

}  // namespace

extern "C" void kernel_launch(void* const* d_in, const int* in_sizes, int n_in,
                              void* d_out, int out_size, void* d_ws, size_t ws_size,
                              hipStream_t stream) {
  const float* sentence = (const float*)d_in[0];
  const int* length     = (const int*)d_in[1];
  const float* ctx_p = (const float*)d_in[2];
  const float* ctx_c = (const float*)d_in[3];
  const float* ctx_h = (const float*)d_in[4];
  const float* W_s[3] = {(const float*)d_in[5],  (const float*)d_in[11], (const float*)d_in[17]};
  const float* b_s[3] = {(const float*)d_in[6],  (const float*)d_in[12], (const float*)d_in[18]};
  const float* W_c[3] = {(const float*)d_in[7],  (const float*)d_in[13], (const float*)d_in[19]};
  const float* b_c[3] = {(const float*)d_in[8],  (const float*)d_in[14], (const float*)d_in[20]};
  const float* v_[3]  = {(const float*)d_in[9],  (const float*)d_in[15], (const float*)d_in[21]};
  float* out = (float*)d_out;

  // workspace layout (bytes) -- sentB eliminated (gemm reads fp32 sentence directly)
  char* ws = (char*)d_ws;
  __bf16* WtB    = (__bf16*)(ws);               // 3*2048*1024*2 = 12582912
  float* ctxb_q  = (float*)(ws + 12582912);     // 4*3*2048*4    = 98304
  float* e_arr   = (float*)(ws + 12681216);     // 3*8192*4      = 98304
  float* stats   = (float*)(ws + 12779520);     // 6 floats

  // 4 graph nodes, no memsets, no cross-kernel atomics except e_arr/out (zeroed in prep).
  k_prep<<<1640, 256, 0, stream>>>(W_s[0], W_s[1], W_s[2], WtB,
                                   ctx_p, ctx_c, ctx_h,
                                   W_c[0], W_c[1], W_c[2],
                                   b_s[0], b_s[1], b_s[2],
                                   b_c[0], b_c[1], b_c[2], ctxb_q, e_arr,
                                   out, out_size);
  k_gemm_e<<<6144, 256, 0, stream>>>(sentence, WtB, ctxb_q,
                                     v_[0], v_[1], v_[2], length, e_arr);
  k_stats<<<3, 256, 0, stream>>>(e_arr, length, stats);
  k_out<<<S / 16, 256, 0, stream>>>(sentence, e_arr, stats, length, out);
}

// Round 10
// 213.542 us; speedup vs baseline: 1.2670x; 1.2670x over previous
//
#include <hip/hip_runtime.h>
#include <hip/hip_bf16.h>
#include <stdint.h>

// Problem: 3x Bahdanau attention (p/c/h heads) -> averaged softmax weights -> weighted sum of sentence.
// S=8192, H2=1024, A=2048, E=768. All inputs fp32; output fp32 [1024].
// R8 (best gemm 54.6us): 64x128, gl_lds A+B, depth-2 vmcnt(3), XCD panel map. Cycle budget:
//     9 LDS ops/wave-iter x 10 waves/CU x ~12cyc ~= 1080 cyc/CU/iter vs 95 cyc MFMA -> LDS-pipe bound.
// R9 (pitch-40): conflicts 2x, 60.1us. R10 (A-direct from fp32 sentence): A loads touch 16 rows
//     at 4KB stride -> 16 scattered lines/instr, vmcnt couples B behind them: 117us. But B-only
//     conflicts measured = 2.85M.
// R11: A stays out of LDS but goes FRAGMENT-MAJOR: prep packs A fragments so a wave's A-frag is
//     ONE coalesced 1KB global_load_dwordx4 (bf16, no cvt, L2-hot via XCD map). LDS = B only
//     (6 ops/wave-iter, 24.8KB -> 5 blocks/CU). Depth-2 counted vmcnt(4) (stage = 2A+2B),
//     3 A-slots + 3 B-bufs statically named (rule #20), sched_barrier-pinned A issues.
// Predicted: gemm ~42us, conflicts ~2.85M (must match R10), MfmaUtil ~21%, occ ~33%.

namespace {

constexpr int S = 8192;
constexpr int H = 1024;   // H2
constexpr int A = 2048;
constexpr int E = 768;

typedef __bf16 bf16x8 __attribute__((ext_vector_type(8)));
typedef float f32x4 __attribute__((ext_vector_type(4)));

__device__ __forceinline__ void gl_lds16(const void* g, void* l) {
  __builtin_amdgcn_global_load_lds(
      (const __attribute__((address_space(1))) void*)g,
      (__attribute__((address_space(3))) void*)l, 16, 0, 0);
}

// ---------- merged prep ----------
// [0,4096)      pack sentence fp32 -> fragment-major bf16 packA (only rows < round_up(len,64))
//               layout: seg(g,kt,f) = ((g*32+kt)*2+f) of 1KB; lane=quad*16+l16 offset 16B.
//               (g=row/32, f=(row/16)&1, l16=row&15, kt=k/32, quad=(k%32)/8)
// [4096,5632)   transpose W_sent fp32 [H][A] -> Wt [A][H] bf16  (float2 in / ushort2 out)
// [5632,5728)   ctxb_q[q][head][a] = partial ctx @ W_ctx over e-quarter q (+biases in q0)
// [5728,5736)   zero e_arr + out
__global__ __launch_bounds__(256)
void k_prep(const float* __restrict__ sentence, __bf16* __restrict__ packA,
            const float* __restrict__ Wp, const float* __restrict__ Wc_s,
            const float* __restrict__ Wh, __bf16* __restrict__ WtB,
            const float* __restrict__ ctx_p, const float* __restrict__ ctx_c,
            const float* __restrict__ ctx_h,
            const float* __restrict__ Wcx_p, const float* __restrict__ Wcx_c,
            const float* __restrict__ Wcx_h,
            const float* __restrict__ bs_p, const float* __restrict__ bs_c,
            const float* __restrict__ bs_h,
            const float* __restrict__ bc_p, const float* __restrict__ bc_c,
            const float* __restrict__ bc_h,
            float* __restrict__ ctxb_q, float* __restrict__ e_arr,
            const int* __restrict__ length, float* __restrict__ out, int n_out) {
  __shared__ float tile[64][65];
  int b = blockIdx.x;
  int t = threadIdx.x;

  if (b < 4096) {
    // ---- phase 1: fragment-pack 2 rows/block, 8 elems/thread ----
    int len = min(max(length[0], 0), S);
    int lenp = (len + 63) & ~63;          // GEMM touches rows < round_up(len,64)
    int row = b * 2 + (t >> 7);
    if (row >= lenp) return;
    int chunk = t & 127;                  // 8-elem chunk within the row
    const float4* s4 = (const float4*)(sentence + (size_t)row * H + chunk * 8);
    float4 lo = s4[0], hi = s4[1];
    bf16x8 o;
    o[0] = (__bf16)lo.x; o[1] = (__bf16)lo.y; o[2] = (__bf16)lo.z; o[3] = (__bf16)lo.w;
    o[4] = (__bf16)hi.x; o[5] = (__bf16)hi.y; o[6] = (__bf16)hi.z; o[7] = (__bf16)hi.w;
    int g = row >> 5, f = (row >> 4) & 1, l16 = row & 15;
    int kt = chunk >> 2, quad = chunk & 3;
    // dst elem offset: seg ((g*32+kt)*2+f) * 512 elems + (quad*16+l16)*8
    size_t dst = ((size_t)((g * 32 + kt) * 2 + f)) * 512 + (quad * 16 + l16) * 8;
    *(bf16x8*)(packA + dst) = o;
  } else if (b < 5632) {
    // ---- phase 2: W_sent [H][A] fp32 -> Wt [A][H] bf16, widened both sides ----
    int r = b - 4096;                 // 512 tiles per head
    int head = r >> 9; r &= 511;
    const float* W = head == 0 ? Wp : (head == 1 ? Wc_s : Wh);
    __bf16* dst = WtB + (size_t)head * A * H;
    int a0 = (r & 31) * 64;           // 32 a-tiles
    int k0 = (r >> 5) * 64;           // 16 k-tiles
#pragma unroll
    for (int i = 0; i < 8; ++i) {
      int idx = t + i * 256;
      int rr = idx >> 5;              // k-row 0..63
      int cc = (idx & 31) * 2;        // a-col pairs
      float2 w2 = *(const float2*)&W[(size_t)(k0 + rr) * A + a0 + cc];
      tile[cc][rr] = w2.x;
      tile[cc + 1][rr] = w2.y;
    }
    __syncthreads();
#pragma unroll
    for (int i = 0; i < 8; ++i) {
      int idx = t + i * 256;
      int al = idx >> 5;              // a-row
      int kl = (idx & 31) * 2;        // k pair
      union { ushort2 u; __bf16 h[2]; } o;
      o.h[0] = (__bf16)tile[al][kl];
      o.h[1] = (__bf16)tile[al][kl + 1];
      *(ushort2*)&dst[(size_t)(a0 + al) * H + k0 + kl] = o.u;
    }
  } else if (b < 5728) {
    // ---- phase 3: ctxb quarter-partials, direct store ----
    int r = b - 5632;                 // 96 blocks: 3 heads x {8 a-blocks x 4 e-quarters}
    int head = r >> 5;
    int sub = r & 31;
    int ablk = sub & 7;
    int eq = sub >> 3;                // e-quarter: 192 elements
    const float* ctx = head == 0 ? ctx_p : (head == 1 ? ctx_c : ctx_h);
    const float* Wc  = head == 0 ? Wcx_p : (head == 1 ? Wcx_c : Wcx_h);
    int a = ablk * 256 + t;
    float s = 0.f;
    if (eq == 0) {
      const float* bs = head == 0 ? bs_p : (head == 1 ? bs_c : bs_h);
      const float* bc = head == 0 ? bc_p : (head == 1 ? bc_c : bc_h);
      s = bs[a] + bc[a];
    }
    int e0 = eq * 192;
#pragma unroll 8
    for (int e = e0; e < e0 + 192; ++e) s = fmaf(ctx[e], Wc[(size_t)e * A + a], s);
    ctxb_q[eq * 3 * A + head * A + a] = s;
  } else {
    // ---- phase 4: zero e_arr (6144 float4) + out ----
    int idx = (b - 5728) * 256 + t;
    float4 z = {0.f, 0.f, 0.f, 0.f};
    int total = 6144 + (n_out >> 2);
    for (int i = idx; i < total; i += 2048) {
      if (i < 6144) ((float4*)e_arr)[i] = z;
      else ((float4*)out)[i - 6144] = z;
    }
  }
}

// ---------- GEMM + fused tanh*v epilogue -> e[head][s] ----------
// 64x128 tile, BK=32. A: fragment-major packed bf16, ONE coalesced 1KB dwordx4 per frag per
// wave (2/iter), never in LDS. B: gl_lds, 3 bufs x 8KB. Depth-2 counted vmcnt(4) (stage(t) =
// 2 A-loads + 2 B-gl_lds; in-loop wait = stage(t+1) landed, stage(t+2) in flight). Raw
// s_barrier + clobber-free waitcnt + sched_barrier(0) pins (R3 lesson; A loads pinned above
// the counted waitcnt). XCD panel-local mapping (R8): xcd=bid&7 owns 6 of 48 panels, m outer.
__global__ __launch_bounds__(256)
void k_gemm_e(const __bf16* __restrict__ packA, const __bf16* __restrict__ WtB,
              const float* __restrict__ ctxb_q,
              const float* __restrict__ v_p, const float* __restrict__ v_c,
              const float* __restrict__ v_h,
              const int* __restrict__ length, float* __restrict__ e_out) {
  int bid = blockIdx.x;
  int xcd = bid & 7;
  int j = bid >> 3;                  // [0, 768)
  int mt = j / 6;                    // m OUTER within XCD: 128 m-tiles
  int pl = j - mt * 6;               // 6 panels per XCD
  int panel = xcd * 6 + pl;          // [0, 48)
  int n0 = (panel & 15) * 128;
  int head = panel >> 4;

  int m0 = mt * 64;
  int len = min(max(length[0], 0), S);
  if (m0 >= len) return;          // masked rows can never influence the softmax
  const float* v  = head == 0 ? v_p : (head == 1 ? v_c : v_h);
  const __bf16* Wt = WtB + (size_t)head * A * H;
  float* e_h = e_out + head * S;

  __shared__ __align__(16) __bf16 lsB[3 * 4096];   // 3 bufs x [128 rows][32 k] = 24 KB
  __shared__ float e_part[64];

  int tid = threadIdx.x;
  if (tid < 64) e_part[tid] = 0.f;   // 33 barriers before the epilogue reads it

  int lane = tid & 63;
  int wave = tid >> 6;
  int wm = wave >> 1, wn = wave & 1;       // wave tile: 32 rows x 64 cols
  int quad = lane >> 4, l16 = lane & 15;

  f32x4 acc[2][4];
#pragma unroll
  for (int i = 0; i < 2; ++i)
#pragma unroll
    for (int j2 = 0; j2 < 4; ++j2) acc[i][j2] = (f32x4){0.f, 0.f, 0.f, 0.f};

  // B staging sources (coalesced 16B/thread)
  const __bf16* gB0 = Wt + (size_t)(n0 + (tid >> 2)) * H + ((tid & 3) * 8);
  const __bf16* gB1 = gB0 + (size_t)64 * H;
  // A fragment source: wave (wm) group g = m0/32 + wm; kt-th tile at seg (g*32+kt)*2 (+f).
  // Per frag: 64 lanes x 16B contiguous -> one fully-coalesced dwordx4 per wave.
  const __bf16* gA = packA + ((size_t)(m0 >> 5) + wm) * 32 * 1024 + (size_t)lane * 8;

  bf16x8 a0f0, a0f1, a1f0, a1f1, a2f0, a2f1;   // 3 static A slots x 2 frags

#define AISSUE(sl, kt)                              \
  do {                                              \
    sl##f0 = *(const bf16x8*)(gA + (size_t)(kt) * 1024);        \
    sl##f1 = *(const bf16x8*)(gA + (size_t)(kt) * 1024 + 512);  \
  } while (0)

#define BISSUE(bufi, kk)                                          \
  do {                                                            \
    gl_lds16(gB0 + (kk), lsB + (bufi) * 4096 + tid * 8);          \
    gl_lds16(gB1 + (kk), lsB + (bufi) * 4096 + 2048 + tid * 8);   \
  } while (0)

#define COMPUTE(sl, bufi)                                                                       \
  do {                                                                                          \
    bf16x8 bfv[4];                                                                              \
    _Pragma("unroll")                                                                           \
    for (int jj = 0; jj < 4; ++jj)                                                              \
      bfv[jj] = *(const bf16x8*)&lsB[(bufi) * 4096 + (wn * 64 + jj * 16 + l16) * 32 + quad * 8];\
    _Pragma("unroll")                                                                           \
    for (int jj = 0; jj < 4; ++jj) {                                                            \
      acc[0][jj] = __builtin_amdgcn_mfma_f32_16x16x32_bf16(sl##f0, bfv[jj], acc[0][jj], 0, 0, 0);\
      acc[1][jj] = __builtin_amdgcn_mfma_f32_16x16x32_bf16(sl##f1, bfv[jj], acc[1][jj], 0, 0, 0);\
    }                                                                                           \
  } while (0)

  // ITER(t): entry invariant = stage(t) consumed-ready (A slot t%3 landed, B buf t%3
  // published), stage(t+1)'s 4 vmem outstanding. Issue stage(t+2) (slot/buf (t+2)%3 --
  // freed at t-1's barrier); COMPUTE(t); pin; wait vmcnt(4) -> stage(t+1) landed; barrier.
#define ITER(t, slI, bufI, slC, bufC)               \
  do {                                              \
    AISSUE(slI, (t) + 2);                           \
    BISSUE(bufI, ((t) + 2) * 32);                   \
    COMPUTE(slC, bufC);                             \
    __builtin_amdgcn_sched_barrier(0);              \
    asm volatile("s_waitcnt vmcnt(4)");             \
    __builtin_amdgcn_sched_barrier(0);              \
    __builtin_amdgcn_s_barrier();                   \
    __builtin_amdgcn_sched_barrier(0);              \
  } while (0)

  // prologue: stage(0), stage(1); wait oldest 4 -> stage(0) landed; barrier publishes B(0).
  AISSUE(a0, 0);
  BISSUE(0, 0);
  AISSUE(a1, 1);
  BISSUE(1, 32);
  __builtin_amdgcn_sched_barrier(0);
  asm volatile("s_waitcnt vmcnt(4)");
  __builtin_amdgcn_sched_barrier(0);
  __builtin_amdgcn_s_barrier();
  __builtin_amdgcn_sched_barrier(0);

#pragma unroll 1
  for (int r = 0; r < 10; ++r) {
    int tb = r * 3;
    ITER(tb + 0, a2, 2, a0, 0);
    ITER(tb + 1, a0, 0, a1, 1);
    ITER(tb + 2, a1, 1, a2, 2);
  }
  // tail: t=30 (slot a0/buf0; stage(31) outstanding), t=31 (slot a1/buf1).
  COMPUTE(a0, 0);
  __builtin_amdgcn_sched_barrier(0);
  asm volatile("s_waitcnt vmcnt(0)");
  __builtin_amdgcn_sched_barrier(0);
  __builtin_amdgcn_s_barrier();
  __builtin_amdgcn_sched_barrier(0);
  COMPUTE(a1, 1);

#undef AISSUE
#undef BISSUE
#undef COMPUTE
#undef ITER

  float vj[4], cbj[4];
#pragma unroll
  for (int j2 = 0; j2 < 4; ++j2) {
    int col = n0 + wn * 64 + j2 * 16 + l16;
    vj[j2] = v[col];
    // sum the 4 e-quarter partials (L2-hot, 98KB table); biases folded into quarter 0
    cbj[j2] = ctxb_q[head * A + col] + ctxb_q[3 * A + head * A + col] +
              ctxb_q[6 * A + head * A + col] + ctxb_q[9 * A + head * A + col];
  }
#pragma unroll
  for (int i = 0; i < 2; ++i) {
#pragma unroll
    for (int r = 0; r < 4; ++r) {
      float p = 0.f;
#pragma unroll
      for (int j2 = 0; j2 < 4; ++j2) {
        float u = acc[i][j2][r] + cbj[j2];
        float ex = __expf(2.f * u);        // tanh = 1 - 2/(e^2x+1); inf-safe at both ends
        float th = 1.f - 2.f / (ex + 1.f);
        p = fmaf(th, vj[j2], p);
      }
      p += __shfl_xor(p, 1);
      p += __shfl_xor(p, 2);
      p += __shfl_xor(p, 4);
      p += __shfl_xor(p, 8);
      if (l16 == 0) atomicAdd(&e_part[wm * 32 + i * 16 + quad * 4 + r], p);
    }
  }
  __syncthreads();
  if (tid < 64) atomicAdd(&e_h[m0 + tid], e_part[tid]);
}

// ---------- softmax stats per head (max, sum) over s < len ----------
__global__ void k_stats(const float* __restrict__ e_arr, const int* __restrict__ length,
                        float* __restrict__ stats) {
  int head = blockIdx.x;
  const float* e_h = e_arr + head * S;
  int len = min(max(length[0], 0), S);
  int tid = threadIdx.x;
  __shared__ float red[4];
  __shared__ float bmax;

  float m = -3.4e38f;
  for (int s = tid; s < len; s += 256) m = fmaxf(m, e_h[s]);
#pragma unroll
  for (int o = 32; o >= 1; o >>= 1) m = fmaxf(m, __shfl_xor(m, o));
  if ((tid & 63) == 0) red[tid >> 6] = m;
  __syncthreads();
  if (tid == 0) bmax = fmaxf(fmaxf(red[0], red[1]), fmaxf(red[2], red[3]));
  __syncthreads();
  float mm = bmax;

  float ss = 0.f;
  for (int s = tid; s < len; s += 256) ss += __expf(e_h[s] - mm);
#pragma unroll
  for (int o = 32; o >= 1; o >>= 1) ss += __shfl_xor(ss, o);
  __syncthreads();
  if ((tid & 63) == 0) red[tid >> 6] = ss;
  __syncthreads();
  if (tid == 0) {
    stats[head * 2 + 0] = mm;
    stats[head * 2 + 1] = red[0] + red[1] + red[2] + red[3];
  }
}

// ---------- out[h] = sum_s w(s) * sentence[s][h], w from e+stats ----------
__global__ void k_out(const float* __restrict__ sent, const float* __restrict__ e_arr,
                      const float* __restrict__ stats, const int* __restrict__ length,
                      float* __restrict__ out) {
  int len = min(max(length[0], 0), S);
  int r0 = blockIdx.x * 16;
  if (r0 >= len) return;
  int tid = threadIdx.x;

  __shared__ float wrow[16];
  if (tid < 16 && r0 + tid < len) {
    int r = r0 + tid;
    wrow[tid] = (__expf(e_arr[r] - stats[0]) / stats[1] +
                 __expf(e_arr[S + r] - stats[2]) / stats[3] +
                 __expf(e_arr[2 * S + r] - stats[4]) / stats[5]) * (1.f / 3.f);
  }
  __syncthreads();

  int col = tid * 4;
  int rend = min(r0 + 16, len);
  float4 acc = {0.f, 0.f, 0.f, 0.f};
  for (int r = r0; r < rend; ++r) {
    float w = wrow[r - r0];
    float4 x = *(const float4*)(sent + (size_t)r * H + col);
    acc.x = fmaf(w, x.x, acc.x);
    acc.y = fmaf(w, x.y, acc.y);
    acc.z = fmaf(w, x.z, acc.z);
    acc.w = fmaf(w, x.w, acc.w);
  }
  atomicAdd(&out[col + 0], acc.x);
  atomicAdd(&out[col + 1], acc.y);
  atomicAdd(&out[col + 2], acc.z);
  atomicAdd(&out[col + 3], acc.w);
}

}  // namespace

extern "C" void kernel_launch(void* const* d_in, const int* in_sizes, int n_in,
                              void* d_out, int out_size, void* d_ws, size_t ws_size,
                              hipStream_t stream) {
  const float* sentence = (const float*)d_in[0];
  const int* length     = (const int*)d_in[1];
  const float* ctx_p = (const float*)d_in[2];
  const float* ctx_c = (const float*)d_in[3];
  const float* ctx_h = (const float*)d_in[4];
  const float* W_s[3] = {(const float*)d_in[5],  (const float*)d_in[11], (const float*)d_in[17]};
  const float* b_s[3] = {(const float*)d_in[6],  (const float*)d_in[12], (const float*)d_in[18]};
  const float* W_c[3] = {(const float*)d_in[7],  (const float*)d_in[13], (const float*)d_in[19]};
  const float* b_c[3] = {(const float*)d_in[8],  (const float*)d_in[14], (const float*)d_in[20]};
  const float* v_[3]  = {(const float*)d_in[9],  (const float*)d_in[15], (const float*)d_in[21]};
  float* out = (float*)d_out;

  // workspace layout (bytes)
  char* ws = (char*)d_ws;
  __bf16* packA  = (__bf16*)(ws);               // 8192*1024*2   = 16777216 (fragment-major)
  __bf16* WtB    = (__bf16*)(ws + 16777216);    // 3*2048*1024*2 = 12582912
  float* ctxb_q  = (float*)(ws + 29360128);     // 4*3*2048*4    = 98304
  float* e_arr   = (float*)(ws + 29458432);     // 3*8192*4      = 98304
  float* stats   = (float*)(ws + 29556736);     // 6 floats

  // 4 graph nodes, no memsets, no cross-kernel atomics except e_arr/out (zeroed in prep).
  k_prep<<<5736, 256, 0, stream>>>(sentence, packA,
                                   W_s[0], W_s[1], W_s[2], WtB,
                                   ctx_p, ctx_c, ctx_h,
                                   W_c[0], W_c[1], W_c[2],
                                   b_s[0], b_s[1], b_s[2],
                                   b_c[0], b_c[1], b_c[2], ctxb_q, e_arr,
                                   length, out, out_size);
  k_gemm_e<<<6144, 256, 0, stream>>>(packA, WtB, ctxb_q,
                                     v_[0], v_[1], v_[2], length, e_arr);
  k_stats<<<3, 256, 0, stream>>>(e_arr, length, stats);
  k_out<<<S / 16, 256, 0, stream>>>(sentence, e_arr, stats, length, out);
}